// Round 13
// baseline (524.589 us; speedup 1.0000x reference)
//
#include <hip/hip_runtime.h>
#include <hip/hip_bf16.h>
#include <math.h>

typedef unsigned short u16;
typedef unsigned long long u64;
#define DEV static __device__ __forceinline__

// ---------------- problem constants ----------------
constexpr int Bz = 2, N0 = 4096, N1 = 1024, N2 = 256, KNN = 20, NA = 12;
constexpr int C0 = 32, C1 = 64, C2 = 128, C3 = 256, C4 = 512;
constexpr int BNG = 32;  // batchnorm atomic groups

// ---------------- workspace layout ----------------
constexpr size_t OFF_V0F   = 0;                       // Bz*N0 float4 (w = |p|^2)
constexpr size_t OFF_V1F   = 32768;
constexpr size_t OFF_V2F   = 40960;
constexpr size_t OFF_K0F   = 43008;                   // 1152
constexpr size_t OFF_DIRS  = 44160;                   // 144
constexpr size_t OFF_WC    = 44304;                   // 174080
constexpr size_t OFF_WS    = 218384;                  // 174080
constexpr size_t OFF_BC    = 392464;                  // 960
constexpr size_t OFF_BN    = 393424;                  // 896
constexpr size_t OFF_FLAG  = 394832;                  // 16
constexpr size_t OFF_IDX0  = 394848;                  // 163840 ints
constexpr size_t OFF_IDX1  = 558688;                  // 40960
constexpr size_t OFF_IDX2  = 599648;                  // 10240
constexpr size_t OFF_PART  = 609888;                  // 28672 floats
constexpr size_t PART_SZ   = 28672;
constexpr size_t OFF_HALF  = OFF_PART + PART_SZ;      // u16 arena base (float offset)

constexpr size_t HA = 0;                              // fm0/fm2
constexpr size_t HB = 3145728;                        // fm1/fm3 ; layer4: fc4 as f32
constexpr size_t HG = 9437184;                        // g1..g4
constexpr size_t HP = HG + 3145728;                   // fmp1/fmp2 (upper half of G)

// output element offsets (float32)
constexpr size_t OUT0 = 0;
constexpr size_t OUT1 = OUT0 + (size_t)Bz*N0*C0;
constexpr size_t OUT2 = OUT1 + (size_t)Bz*N0*C1;
constexpr size_t OUT3 = OUT2 + (size_t)Bz*N1*C2;
constexpr size_t OUT4 = OUT3 + (size_t)Bz*N1*C3;

DEV float b2f(u16 v) { return __uint_as_float(((unsigned int)v) << 16); }
DEV u16 f2b(float f) {
  unsigned int u = __float_as_uint(f);
  unsigned int lsb = (u >> 16) & 1u;
  return (u16)((u + 0x7fffu + lsb) >> 16);
}
DEV unsigned packb(float a, float b) {
  return (unsigned)f2b(a) | ((unsigned)f2b(b) << 16);
}

DEV u64 shflx64(u64 v, int m) {
  int lo = __shfl_xor((int)(unsigned)v, m, 64);
  int hi = __shfl_xor((int)(unsigned)(v >> 32), m, 64);
  return ((u64)(unsigned)hi << 32) | (unsigned)lo;
}
DEV int mbcnt64(u64 m) {
  return __builtin_amdgcn_mbcnt_hi((unsigned)(m >> 32),
         __builtin_amdgcn_mbcnt_lo((unsigned)m, 0));
}

DEV void st12(float* dst, const float* v) {
  float4 a{v[0],v[1],v[2],v[3]}, b{v[4],v[5],v[6],v[7]}, c{v[8],v[9],v[10],v[11]};
  ((float4*)dst)[0] = a; ((float4*)dst)[1] = b; ((float4*)dst)[2] = c;
}
DEV void st12(u16* dst, const float* v) {
  uint2 a{packb(v[0],v[1]), packb(v[2],v[3])};
  uint2 b{packb(v[4],v[5]), packb(v[6],v[7])};
  uint2 c{packb(v[8],v[9]), packb(v[10],v[11])};
  ((uint2*)dst)[0] = a; ((uint2*)dst)[1] = b; ((uint2*)dst)[2] = c;
}

// ---------------- dtype detect + zero bn partials ----------------
__global__ void eq_detect(const u16* __restrict__ v, int* __restrict__ flag,
                          float* __restrict__ part) {
  int tid = threadIdx.x;
  for (int i = tid; i < (int)PART_SZ; i += 256) part[i] = 0.f;
  if (tid < 64) {
    int bad = 0;
    #pragma unroll
    for (int j = 0; j < 4; ++j) {
      unsigned u = v[tid*4 + j];
      int ex = (u >> 7) & 0xFF;
      bad += (((u & 0x7FFFu) != 0u) && (ex < 64 || ex > 191)) ? 1 : 0;
    }
    int tot = bad;
    #pragma unroll
    for (int s = 32; s > 0; s >>= 1) tot += __shfl_xor(tot, s, 64);
    if (tid == 0) *flag = (tot >= 8) ? 1 : 0;   // 1 => inputs are f32
  }
}

// ---------------- convert all inputs -> f32 in ws (+v1f/v2f subsamples) ----------------
struct InPtrs { const void* p[24]; };

__global__ void eq_convert_all(InPtrs in, float* ws) {
  int f32mode = *(volatile int*)(ws + OFF_FLAG);
  int t = blockIdx.x * blockDim.x + threadIdx.x;
  if (t < Bz*N0) {      // one thread per point; w = |p|^2
    float x, y, z;
    if (f32mode) { const float* v = (const float*)in.p[0]; x=v[t*3]; y=v[t*3+1]; z=v[t*3+2]; }
    else { const u16* v = (const u16*)in.p[0]; x=b2f(v[t*3]); y=b2f(v[t*3+1]); z=b2f(v[t*3+2]); }
    float4 o; o.x=x; o.y=y; o.z=z; o.w=(x*x + y*y) + z*z;
    ((float4*)(ws + OFF_V0F))[t] = o;
    int b = t / N0, i = t % N0;
    if ((i & 3) == 0)  ((float4*)(ws + OFF_V1F))[b*N1 + (i >> 2)] = o;
    if ((i & 15) == 0) ((float4*)(ws + OFF_V2F))[b*N2 + (i >> 4)] = o;
    return;
  }
  int r = t - Bz*N0;
  const int cnt[23] = {1152, 36,2048,64,2048, 36,8192,128,8192,
                       36,32768,256,32768, 36,131072,512,131072,
                       64,64,128,128,256,256};
  const size_t off[23] = {OFF_K0F,
    OFF_DIRS+0,   OFF_WC+0,     OFF_BC+0,   OFF_WS+0,
    OFF_DIRS+36,  OFF_WC+2048,  OFF_BC+64,  OFF_WS+2048,
    OFF_DIRS+72,  OFF_WC+10240, OFF_BC+192, OFF_WS+10240,
    OFF_DIRS+108, OFF_WC+43008, OFF_BC+448, OFF_WS+43008,
    OFF_BN+0, OFF_BN+64, OFF_BN+128, OFF_BN+256, OFF_BN+384, OFF_BN+640};
  for (int i = 0; i < 23; ++i) {
    if (r < cnt[i]) {
      float val = f32mode ? ((const float*)in.p[i+1])[r] : b2f(((const u16*)in.p[i+1])[r]);
      ws[off[i] + r] = val;
      return;
    }
    r -= cnt[i];
  }
}

// ---------------- KNN body (v4 logic as device fn; smem passed in) ----------------
template<int NPTS>
DEV void knn_body(int blk, const float4* __restrict__ vf, int* __restrict__ idx_out,
                  char* smem) {
  constexpr int CPL = NPTS/64;
  constexpr int TILE = (NPTS < 512) ? NPTS : 512;
  constexpr int NT = NPTS / TILE;
  float4* tile = (float4*)smem;
  u64* selw_base = (u64*)(smem + TILE*16);
  int* extr_base = (int*)(smem + TILE*16 + 4*64*8);
  int wave = threadIdx.x >> 6, lane = threadIdx.x & 63;
  int tid = threadIdx.x;
  u64* selw = selw_base + wave*64;
  int* extrw = extr_base + wave*24;
  int qid = blk*4 + wave;
  int b = qid / NPTS, q = qid % NPTS;
  const float4* vb = vf + (size_t)b*NPTS;
  float4 vq = vb[q];
  const unsigned DINF = 0xFFFFFFFFu;
  unsigned d1=DINF, d2=DINF, d3=DINF, d4=DINF;
  int i1=0x3FFFFFFF, i2=0x3FFFFFFF, i3=0x3FFFFFFF, i4=0x3FFFFFFF;
  for (int tt = 0; tt < NT; ++tt) {
    __syncthreads();
    for (int i = tid; i < TILE; i += 256) tile[i] = vb[tt*TILE + i];
    __syncthreads();
    #pragma unroll 4
    for (int j = 0; j < TILE/64; ++j) {
      int cl = j*64 + lane;
      float4 vc = tile[cl];
      int c = tt*TILE + cl;
      float dt = (vq.x*vc.x + vq.y*vc.y) + vq.z*vc.z;
      float d = (vq.w + vc.w) - 2.0f*dt;
      unsigned u = __float_as_uint(d);
      unsigned ud = u ^ ((unsigned)(((int)u) >> 31) | 0x80000000u);  // monotone
      bool lt1 = ud < d1, lt2 = ud < d2, lt3 = ud < d3, lt4 = ud < d4;
      d4 = lt3 ? d3 : (lt4 ? ud : d4);  i4 = lt3 ? i3 : (lt4 ? c : i4);
      d3 = lt2 ? d2 : (lt3 ? ud : d3);  i3 = lt2 ? i2 : (lt3 ? c : i3);
      d2 = lt1 ? d1 : (lt2 ? ud : d2);  i2 = lt1 ? i1 : (lt2 ? c : i2);
      d1 = lt1 ? ud : d1;               i1 = lt1 ? c  : i1;
    }
  }
  unsigned p = 0;
  for (int bit = 31; bit >= 0; --bit) {
    unsigned T = p | (1u << bit);
    u64 m1 = __ballot(d1 < T), m2 = __ballot(d2 < T);
    u64 m3 = __ballot(d3 < T), m4 = __ballot(d4 < T);
    int cnt = __popcll(m1) + __popcll(m2) + __popcll(m3) + __popcll(m4);
    if (cnt < KNN+1) p = T;
  }
  size_t obase = (size_t)qid*KNN;
  bool need_fb = false;
  if (CPL > 4) {
    need_fb = (__ballot(d4 <= p) != 0ULL);
  }
  if (!need_fb) {
    bool p1 = d1 <= p, p2 = d2 <= p, p3 = d3 <= p, p4 = d4 <= p;
    u64 m1 = __ballot(p1), m2 = __ballot(p2), m3 = __ballot(p3), m4 = __ballot(p4);
    int c1 = __popcll(m1), c2 = __popcll(m2), c3 = __popcll(m3), c4 = __popcll(m4);
    int S = c1 + c2 + c3 + c4;
    if (S > 63) need_fb = true;
    else {
      if (p1) selw[mbcnt64(m1)] = ((u64)d1 << 32) | (unsigned)i1;
      if (p2) selw[c1 + mbcnt64(m2)] = ((u64)d2 << 32) | (unsigned)i2;
      if (p3) selw[c1 + c2 + mbcnt64(m3)] = ((u64)d3 << 32) | (unsigned)i3;
      if (p4) selw[c1 + c2 + c3 + mbcnt64(m4)] = ((u64)d4 << 32) | (unsigned)i4;
      if (lane < S) {
        u64 mykey = selw[lane];
        int rank = 0;
        for (int j = 0; j < S; ++j) rank += (selw[j] < mykey) ? 1 : 0;
        if (rank >= 1 && rank <= KNN)
          idx_out[obase + rank - 1] = (int)(unsigned)(mykey & 0xFFFFFFFFu);
      }
    }
  }
  if (need_fb) {
    const u64 KINF = ~0ULL;
    u64 k1 = ((u64)d1 << 32) | (unsigned)i1;
    u64 k2 = ((u64)d2 << 32) | (unsigned)i2;
    u64 k3 = ((u64)d3 << 32) | (unsigned)i3;
    u64 k4 = ((u64)d4 << 32) | (unsigned)i4;
    for (int r = 0; r < KNN+1; ++r) {
      u64 g = k1;
      #pragma unroll
      for (int s = 32; s; s >>= 1) { u64 o = shflx64(g, s); g = (o < g) ? o : g; }
      int gidx = (int)(g & 0xFFFFFFFFu);
      if (lane == 0) {
        extrw[r] = gidx;
        if (r > 0) idx_out[obase + r - 1] = gidx;
      }
      if (r < KNN && lane == (gidx & 63)) {
        k1 = k2; k2 = k3; k3 = k4; k4 = KINF;
        if (k1 == KINF) {
          for (int j = 0; j < CPL; ++j) {
            int c = j*64 + lane;
            float4 vc = vb[c];
            float dt = (vq.x*vc.x + vq.y*vc.y) + vq.z*vc.z;
            float d = (vq.w + vc.w) - 2.0f*dt;
            unsigned u = __float_as_uint(d);
            unsigned ud = u ^ ((unsigned)(((int)u) >> 31) | 0x80000000u);
            u64 k = ((u64)ud << 32) | (unsigned)c;
            bool ex = false;
            for (int e = 0; e <= r; ++e) ex |= (extrw[e] == c);
            if (!ex) {
              bool lt1 = k < k1, lt2 = k < k2, lt3 = k < k3, lt4 = k < k4;
              k4 = lt3 ? k3 : (lt4 ? k : k4);
              k3 = lt2 ? k2 : (lt3 ? k : k3);
              k2 = lt1 ? k1 : (lt2 ? k : k2);
              k1 = lt1 ? k  : k1;
            }
          }
        }
      }
    }
  }
}

// ---------------- fused KNN: all 3 levels in one dispatch ----------------
__global__ __launch_bounds__(256) void eq_knn_all(
    const float4* __restrict__ v0, int* __restrict__ i0,
    const float4* __restrict__ v1, int* __restrict__ i1,
    const float4* __restrict__ v2, int* __restrict__ i2) {
  __shared__ __align__(16) char smem[512*16 + 4*64*8 + 4*24*4];
  int blk = blockIdx.x;
  constexpr int NB0 = Bz*N0/4, NB1 = Bz*N1/4;
  if (blk < NB0)            knn_body<N0>(blk, v0, i0, smem);
  else if (blk < NB0+NB1)   knn_body<N1>(blk - NB0, v1, i1, smem);
  else                      knn_body<N2>(blk - NB0 - NB1, v2, i2, smem);
}

// ---------------- conv_surface + relu + fea_of(fm0), vectorized stores ----------------
__global__ __launch_bounds__(128) void eq_conv_surface(
    const float4* __restrict__ v0f, const int* __restrict__ idx0,
    const float* __restrict__ K0f, u16* __restrict__ fm0, float* __restrict__ out0) {
  int bq = blockIdx.x;          // b*N0 + q
  int b = bq >> 12;
  __shared__ float dk[KNN][3];
  __shared__ float row[C0*NA];
  int tid = threadIdx.x;
  if (tid < KNN) {
    int m = idx0[(size_t)bq*KNN + tid];
    float4 vq = v0f[bq];
    float4 vm = v0f[(size_t)b*N0 + m];
    float dx = vm.x - vq.x, dy = vm.y - vq.y, dz = vm.z - vq.z;
    float nrm = sqrtf((dx*dx + dy*dy) + dz*dz) + 1e-8f;
    dk[tid][0] = dx/nrm; dk[tid][1] = dy/nrm; dk[tid][2] = dz/nrm;
  }
  __syncthreads();
  for (int t4 = tid; t4 < C0*NA/4; t4 += 128) {
    const float* kd = K0f + (size_t)t4*12;
    float4 k0 = *(const float4*)(kd);
    float4 k1 = *(const float4*)(kd + 4);
    float4 k2 = *(const float4*)(kd + 8);
    float m0=0.f, m1=0.f, m2=0.f, m3=0.f;   // relu then max => >= 0
    #pragma unroll
    for (int k = 0; k < KNN; ++k) {
      float dx = dk[k][0], dy = dk[k][1], dz = dk[k][2];
      m0 = fmaxf(m0, (dx*k0.x + dy*k0.y) + dz*k0.z);
      m1 = fmaxf(m1, (dx*k0.w + dy*k1.x) + dz*k1.y);
      m2 = fmaxf(m2, (dx*k1.z + dy*k1.w) + dz*k2.x);
      m3 = fmaxf(m3, (dx*k2.y + dy*k2.z) + dz*k2.w);
    }
    uint2 r; r.x = packb(m0, m1); r.y = packb(m2, m3);
    ((uint2*)fm0)[(size_t)bq*(C0*NA/4) + t4] = r;
    row[4*t4+0] = m0; row[4*t4+1] = m1; row[4*t4+2] = m2; row[4*t4+3] = m3;
  }
  __syncthreads();
  if (tid < C0) {
    float m = row[tid*NA];
    #pragma unroll
    for (int a = 1; a < NA; ++a) m = fmaxf(m, row[tid*NA + a]);
    out0[(size_t)bq*C0 + tid] = m;
  }
}

// ---------------- linear v4: one matrix per block (blockIdx&1), o fast index ----
template<int CI, int CO, typename TO>
__global__ __launch_bounds__(256) void eq_linear4(
    const u16* __restrict__ in, const float* __restrict__ Wc,
    const float* __restrict__ Ws, const float* __restrict__ bias,
    TO* __restrict__ fc, u16* __restrict__ g) {
  constexpr int PPB = 512 / CO;
  constexpr int RS = CI*NA + 4;
  __shared__ float lds[PPB*RS];
  int tid = threadIdx.x;
  int mat = blockIdx.x & 1;
  int pt0 = (blockIdx.x >> 1) * PPB;
  constexpr int E = PPB*CI*NA;
  for (int t = tid; t < E; t += 256) {
    int pt = t / (CI*NA), r = t % (CI*NA);
    lds[pt*RS + r] = b2f(in[((size_t)(pt0+pt))*CI*NA + r]);
  }
  __syncthreads();
  constexpr int TPP = CO/2;
  int opair = tid % TPP, pt = tid / TPP;
  int o0 = opair*2;
  const float* W = mat ? Ws : Wc;
  const float* row = lds + pt*RS;
  float a0[NA], a1[NA];
  #pragma unroll
  for (int a = 0; a < NA; ++a) { a0[a]=0.f; a1[a]=0.f; }
  #pragma unroll 4
  for (int c = 0; c < CI; ++c) {
    float2 w2 = *(const float2*)(W + (size_t)c*CO + o0);
    float4 i0 = *(const float4*)(row + c*NA);
    float4 i1 = *(const float4*)(row + c*NA + 4);
    float4 i2 = *(const float4*)(row + c*NA + 8);
    float iv[NA] = {i0.x,i0.y,i0.z,i0.w, i1.x,i1.y,i1.z,i1.w, i2.x,i2.y,i2.z,i2.w};
    #pragma unroll
    for (int a = 0; a < NA; ++a) {
      a0[a] += iv[a]*w2.x; a1[a] += iv[a]*w2.y;
    }
  }
  size_t ptg = pt0 + pt;
  if (mat == 0) {
    float b0 = bias[o0], b1 = bias[o0+1];
    #pragma unroll
    for (int a = 0; a < NA; ++a) { a0[a] += b0; a1[a] += b1; }
    st12(fc + ((size_t)ptg*CO + o0)*NA, a0);
    st12(fc + ((size_t)ptg*CO + o0 + 1)*NA, a1);
  } else {
    st12(g + ((size_t)ptg*CO + o0)*NA, a0);
    st12(g + ((size_t)ptg*CO + o0 + 1)*NA, a1);
  }
}

// ---------------- fsmax + fused BN partial stats (full-unroll k loop) ----------------
__global__ __launch_bounds__(256) void eq_fsmax(
    const u16* __restrict__ g, const float4* __restrict__ vf,
    const float* __restrict__ dirs, const int* __restrict__ idx,
    u16* __restrict__ out, float* __restrict__ part, int npts, int co) {
  int bq = blockIdx.x;
  int b = bq / npts;
  __shared__ float th[KNN*NA];
  __shared__ float dk[KNN][3];
  __shared__ int nb[KNN];
  __shared__ float sstat[2][C3];     // co <= 256
  int tid = threadIdx.x;
  if (tid < KNN) {
    int m = idx[(size_t)bq*KNN + tid];
    nb[tid] = m;
    float4 vq = vf[bq];
    float4 vm = vf[(size_t)b*npts + m];
    float dx = vm.x - vq.x, dy = vm.y - vq.y, dz = vm.z - vq.z;
    float nrm = sqrtf((dx*dx + dy*dy) + dz*dz) + 1e-8f;
    dk[tid][0] = dx/nrm; dk[tid][1] = dy/nrm; dk[tid][2] = dz/nrm;
  }
  sstat[0][tid] = 0.f; sstat[1][tid] = 0.f;
  __syncthreads();
  if (tid < KNN*NA) {
    int k = tid / NA, a = tid % NA;
    float s = (dk[k][0]*dirs[a*3] + dk[k][1]*dirs[a*3+1]) + dk[k][2]*dirs[a*3+2];
    th[tid] = fmaxf(s, 0.f);
  }
  __syncthreads();
  int quarter = co*NA/4;
  uint2* dst = (uint2*)(out + (size_t)bq*co*NA);
  const uint2* gb = (const uint2*)(g + (size_t)b*npts*co*NA);
  for (int t4 = tid; t4 < quarter; t4 += 256) {
    int a = (4*t4) % NA;          // 0, 4, or 8 — quad never straddles an o-row
    const float* tha = th + a;
    float m0=-3.0e38f, m1=-3.0e38f, m2=-3.0e38f, m3=-3.0e38f;
    #pragma unroll
    for (int k = 0; k < KNN; ++k) {
      uint2 pv = gb[(size_t)nb[k]*quarter + t4];
      float t0 = tha[k*NA+0], t1 = tha[k*NA+1], t2 = tha[k*NA+2], t3 = tha[k*NA+3];
      m0 = fmaxf(m0, t0*b2f((u16)(pv.x)));
      m1 = fmaxf(m1, t1*b2f((u16)(pv.x >> 16)));
      m2 = fmaxf(m2, t2*b2f((u16)(pv.y)));
      m3 = fmaxf(m3, t3*b2f((u16)(pv.y >> 16)));
    }
    uint2 d = dst[t4];
    float v0 = b2f((u16)d.x) + m0;
    float v1 = b2f((u16)(d.x >> 16)) + m1;
    float v2 = b2f((u16)d.y) + m2;
    float v3 = b2f((u16)(d.y >> 16)) + m3;
    uint2 r; r.x = packb(v0, v1); r.y = packb(v2, v3);
    dst[t4] = r;
    int ch = t4 / 3;              // NA/4 = 3 quads per channel
    atomicAdd(&sstat[0][ch], (v0 + v1) + (v2 + v3));
    atomicAdd(&sstat[1][ch], (v0*v0 + v1*v1) + (v2*v2 + v3*v3));
  }
  __syncthreads();
  if (tid < co) {
    float* pg = part + (size_t)(bq & (BNG-1))*2*co;
    atomicAdd(&pg[tid], sstat[0][tid]);
    atomicAdd(&pg[co + tid], sstat[1][tid]);
  }
}

// ---------------- layer4: fsmax + fea_of fused, channel-split, vectorized ----------------
template<int SPL>
__global__ __launch_bounds__(256) void eq_fsmax_fea(
    const u16* __restrict__ g, const float* __restrict__ fcin,
    const float4* __restrict__ vf, const float* __restrict__ dirs,
    const int* __restrict__ idx, float* __restrict__ outfea,
    int npts, int co) {
  constexpr int CHUNK = C4 / SPL;
  int part = blockIdx.x % SPL;
  int bq = blockIdx.x / SPL;
  int b = bq / npts;
  __shared__ float th[KNN*NA];
  __shared__ float dk[KNN][3];
  __shared__ int nb[KNN];
  __shared__ float row[CHUNK*NA];
  int tid = threadIdx.x;
  if (tid < KNN) {
    int m = idx[(size_t)bq*KNN + tid];
    nb[tid] = m;
    float4 vq = vf[bq];
    float4 vm = vf[(size_t)b*npts + m];
    float dx = vm.x - vq.x, dy = vm.y - vq.y, dz = vm.z - vq.z;
    float nrm = sqrtf((dx*dx + dy*dy) + dz*dz) + 1e-8f;
    dk[tid][0] = dx/nrm; dk[tid][1] = dy/nrm; dk[tid][2] = dz/nrm;
  }
  __syncthreads();
  if (tid < KNN*NA) {
    int k = tid / NA, a = tid % NA;
    float s = (dk[k][0]*dirs[a*3] + dk[k][1]*dirs[a*3+1]) + dk[k][2]*dirs[a*3+2];
    th[tid] = fmaxf(s, 0.f);
  }
  __syncthreads();
  int o0 = part * CHUNK;
  const float4* fcr = (const float4*)(fcin + ((size_t)bq*co + o0)*NA);
  const uint2* gb = (const uint2*)(g + (size_t)b*npts*co*NA + (size_t)o0*NA);
  int gquarter = co*NA/4;
  for (int t4 = tid; t4 < CHUNK*NA/4; t4 += 256) {
    int a = (4*t4) % NA;
    const float* tha = th + a;
    float m0=-3.0e38f, m1=-3.0e38f, m2=-3.0e38f, m3=-3.0e38f;
    #pragma unroll
    for (int k = 0; k < KNN; ++k) {
      uint2 pv = gb[(size_t)nb[k]*gquarter + t4];
      float t0 = tha[k*NA+0], t1 = tha[k*NA+1], t2 = tha[k*NA+2], t3 = tha[k*NA+3];
      m0 = fmaxf(m0, t0*b2f((u16)(pv.x)));
      m1 = fmaxf(m1, t1*b2f((u16)(pv.x >> 16)));
      m2 = fmaxf(m2, t2*b2f((u16)(pv.y)));
      m3 = fmaxf(m3, t3*b2f((u16)(pv.y >> 16)));
    }
    float4 fc4 = fcr[t4];
    row[4*t4+0] = fc4.x + m0;
    row[4*t4+1] = fc4.y + m1;
    row[4*t4+2] = fc4.z + m2;
    row[4*t4+3] = fc4.w + m3;
  }
  __syncthreads();
  for (int o = tid; o < CHUNK; o += 256) {
    float m = row[o*NA];
    #pragma unroll
    for (int a = 1; a < NA; ++a) m = fmaxf(m, row[o*NA + a]);
    outfea[(size_t)bq*co + o0 + o] = m;
  }
}

// ---------------- normalize + relu (in place) + fea_of (folds BNG partials) ----------------
__global__ __launch_bounds__(256) void eq_bnrelu_fea(
    u16* __restrict__ fm, const float* __restrict__ part,
    const float* __restrict__ gamma, const float* __restrict__ beta,
    float* __restrict__ outfea, int npts, int co) {
  int bq = blockIdx.x;
  int tid = threadIdx.x;
  __shared__ float sc[C3], sh[C3];
  __shared__ float row[C3*NA];
  for (int o = tid; o < co; o += 256) {
    float s = 0.f, s2 = 0.f;
    for (int g = 0; g < BNG; ++g) {
      s  += part[(size_t)g*2*co + o];
      s2 += part[(size_t)g*2*co + co + o];
    }
    float cnt = (float)(Bz*npts*NA);
    float mean = s / cnt;
    float var = fmaxf(s2 / cnt - mean*mean, 0.f);
    float inv = 1.0f / sqrtf(var + 1e-5f);
    sc[o] = gamma[o] * inv;
    sh[o] = beta[o] - mean * gamma[o] * inv;
  }
  __syncthreads();
  uint2* p = (uint2*)(fm + (size_t)bq*co*NA);
  int quarter = co*NA/4;
  for (int t4 = tid; t4 < quarter; t4 += 256) {
    int o = (4*t4) / NA;            // quad never straddles o-row
    float s = sc[o], h = sh[o];
    uint2 pv = p[t4];
    float v0 = fmaxf(b2f((u16)pv.x)*s + h, 0.f);
    float v1 = fmaxf(b2f((u16)(pv.x >> 16))*s + h, 0.f);
    float v2 = fmaxf(b2f((u16)pv.y)*s + h, 0.f);
    float v3 = fmaxf(b2f((u16)(pv.y >> 16))*s + h, 0.f);
    uint2 r; r.x = packb(v0, v1); r.y = packb(v2, v3);
    p[t4] = r;
    row[4*t4+0] = v0; row[4*t4+1] = v1; row[4*t4+2] = v2; row[4*t4+3] = v3;
  }
  __syncthreads();
  for (int o = tid; o < co; o += 256) {
    float m = row[o*NA];
    #pragma unroll
    for (int a = 1; a < NA; ++a) m = fmaxf(m, row[o*NA + a]);
    outfea[(size_t)bq*co + o] = m;
  }
}

// ---------------- pool (vectorized): fmp = max(fm[4j], max_k fm[nb]) ----------------
__global__ __launch_bounds__(256) void eq_pool(
    const u16* __restrict__ fm, const int* __restrict__ idx,
    u16* __restrict__ fmp, int npts, int c) {
  int ns = npts / 4;
  int bj = blockIdx.x;
  int b = bj / ns, j = bj % ns;
  int q = 4*j;
  size_t bq = (size_t)b*npts + q;
  __shared__ int nb[4];
  if (threadIdx.x < 4) nb[threadIdx.x] = idx[bq*KNN + threadIdx.x];
  __syncthreads();
  int quarter = c*NA/4;
  const uint2* base = (const uint2*)(fm + (size_t)b*npts*c*NA);
  const uint2* p0 = base + (size_t)q*quarter;
  uint2* dst = (uint2*)(fmp + (size_t)bj*c*NA);
  for (int t4 = threadIdx.x; t4 < quarter; t4 += 256) {
    uint2 v = p0[t4];
    float m0 = b2f((u16)v.x), m1 = b2f((u16)(v.x >> 16));
    float m2 = b2f((u16)v.y), m3 = b2f((u16)(v.y >> 16));
    #pragma unroll
    for (int kk = 0; kk < 4; ++kk) {
      uint2 w = base[(size_t)nb[kk]*quarter + t4];
      m0 = fmaxf(m0, b2f((u16)w.x));
      m1 = fmaxf(m1, b2f((u16)(w.x >> 16)));
      m2 = fmaxf(m2, b2f((u16)w.y));
      m3 = fmaxf(m3, b2f((u16)(w.y >> 16)));
    }
    uint2 r; r.x = packb(m0, m1); r.y = packb(m2, m3);
    dst[t4] = r;
  }
}

// ---------------- host orchestration ----------------
extern "C" void kernel_launch(void* const* d_in, const int* in_sizes, int n_in,
                              void* d_out, int out_size, void* d_ws, size_t ws_size,
                              hipStream_t stream) {
  float* ws = (float*)d_ws;
  float* out = (float*)d_out;
  u16* arena = (u16*)(ws + OFF_HALF);

  InPtrs ip;
  for (int i = 0; i < 24; ++i) ip.p[i] = d_in[i];

  float4* v0f = (float4*)(ws + OFF_V0F);
  float4* v1f = (float4*)(ws + OFF_V1F);
  float4* v2f = (float4*)(ws + OFF_V2F);
  int* idx0 = (int*)(ws + OFF_IDX0);
  int* idx1 = (int*)(ws + OFF_IDX1);
  int* idx2 = (int*)(ws + OFF_IDX2);
  u16* bufA = arena + HA;            // fm0 -> fm2
  u16* bufB = arena + HB;            // fm1 -> fm3
  float* fc4f = (float*)(arena + HB);// layer4 fc carrier (fm3 dead by then)
  u16* bufG = arena + HG;            // g (Ws-transformed)
  u16* bufP = arena + HP;            // fmp1/fmp2 (upper half of G)
  float* partA = ws + OFF_PART;            // 32 x 2*C1
  float* partB = ws + OFF_PART + 4096;     // 32 x 2*C2
  float* partC = ws + OFF_PART + 12288;    // 32 x 2*C3
  const float* DIRS = ws + OFF_DIRS;

  // 0) dtype detect + zero bn partials; convert all inputs (+ v1f/v2f subsamples)
  eq_detect<<<1, 256, 0, stream>>>((const u16*)d_in[0], (int*)(ws + OFF_FLAG), ws + OFF_PART);
  {
    int total = Bz*N0 + 351312;
    eq_convert_all<<<(total + 255)/256, 256, 0, stream>>>(ip, ws);
  }

  // 1) all 3 KNN levels in one dispatch (all depend only on convert)
  eq_knn_all<<<Bz*N0/4 + Bz*N1/4 + Bz*N2/4, 256, 0, stream>>>(v0f, idx0, v1f, idx1, v2f, idx2);
  eq_conv_surface<<<Bz*N0, 128, 0, stream>>>(v0f, idx0, ws + OFF_K0F, bufA, out + OUT0);

  // 2) layer1: fm0(bufA,C0) -> fm1(bufB,C1) at N0
  eq_linear4<C0, C1, u16><<<(Bz*N0/8)*2, 256, 0, stream>>>(bufA, ws + OFF_WC + 0, ws + OFF_WS + 0,
                                                           ws + OFF_BC + 0, bufB, bufG);
  eq_fsmax<<<Bz*N0, 256, 0, stream>>>(bufG, v0f, DIRS + 0, idx0, bufB, partA, N0, C1);
  eq_bnrelu_fea<<<Bz*N0, 256, 0, stream>>>(bufB, partA, ws + OFF_BN + 0, ws + OFF_BN + 64,
                                           out + OUT1, N0, C1);

  // 3) pool1: fm1(bufB) -> fmp1(bufP,C1) at N1
  eq_pool<<<Bz*N1, 256, 0, stream>>>(bufB, idx0, bufP, N0, C1);

  // 4) layer2: fmp1(bufP,C1) -> fm2(bufA,C2) at N1
  eq_linear4<C1, C2, u16><<<(Bz*N1/4)*2, 256, 0, stream>>>(bufP, ws + OFF_WC + 2048, ws + OFF_WS + 2048,
                                                           ws + OFF_BC + 64, bufA, bufG);
  eq_fsmax<<<Bz*N1, 256, 0, stream>>>(bufG, v1f, DIRS + 36, idx1, bufA, partB, N1, C2);
  eq_bnrelu_fea<<<Bz*N1, 256, 0, stream>>>(bufA, partB, ws + OFF_BN + 128, ws + OFF_BN + 256,
                                           out + OUT2, N1, C2);

  // 5) layer3: fm2(bufA,C2) -> fm3(bufB,C3) at N1
  eq_linear4<C2, C3, u16><<<(Bz*N1/2)*2, 256, 0, stream>>>(bufA, ws + OFF_WC + 10240, ws + OFF_WS + 10240,
                                                           ws + OFF_BC + 192, bufB, bufG);
  eq_fsmax<<<Bz*N1, 256, 0, stream>>>(bufG, v1f, DIRS + 72, idx1, bufB, partC, N1, C3);
  eq_bnrelu_fea<<<Bz*N1, 256, 0, stream>>>(bufB, partC, ws + OFF_BN + 384, ws + OFF_BN + 640,
                                           out + OUT3, N1, C3);

  // 6) pool2: fm3(bufB,C3) -> fmp2(bufP,C3) at N2
  eq_pool<<<Bz*N2, 256, 0, stream>>>(bufB, idx1, bufP, N1, C3);

  // 7) layer4: fmp2(bufP,C3) -> fc4(f32) + g; fused fsmax+fea (4-way split) -> out4
  eq_linear4<C3, C4, float><<<(Bz*N2)*2, 256, 0, stream>>>(bufP, ws + OFF_WC + 43008, ws + OFF_WS + 43008,
                                                           ws + OFF_BC + 448, fc4f, bufG);
  eq_fsmax_fea<4><<<Bz*N2*4, 256, 0, stream>>>(bufG, fc4f, v2f, DIRS + 108, idx2, out + OUT4, N2, C4);
}

// Round 14
// 498.135 us; speedup vs baseline: 1.0531x; 1.0531x over previous
//
#include <hip/hip_runtime.h>
#include <hip/hip_bf16.h>
#include <math.h>

typedef unsigned short u16;
typedef unsigned long long u64;
#define DEV static __device__ __forceinline__

// ---------------- problem constants ----------------
constexpr int Bz = 2, N0 = 4096, N1 = 1024, N2 = 256, KNN = 20, NA = 12;
constexpr int C0 = 32, C1 = 64, C2 = 128, C3 = 256, C4 = 512;
constexpr int BNG = 32;  // batchnorm atomic groups

// ---------------- workspace layout ----------------
constexpr size_t OFF_V0F   = 0;                       // Bz*N0 float4 (w = |p|^2)
constexpr size_t OFF_V1F   = 32768;
constexpr size_t OFF_V2F   = 40960;
constexpr size_t OFF_K0F   = 43008;                   // 1152
constexpr size_t OFF_DIRS  = 44160;                   // 144
constexpr size_t OFF_WC    = 44304;                   // 174080
constexpr size_t OFF_WS    = 218384;                  // 174080
constexpr size_t OFF_BC    = 392464;                  // 960
constexpr size_t OFF_BN    = 393424;                  // 896
constexpr size_t OFF_FLAG  = 394832;                  // 16 (unused now)
constexpr size_t OFF_IDX0  = 394848;                  // 163840 ints
constexpr size_t OFF_IDX1  = 558688;                  // 40960
constexpr size_t OFF_IDX2  = 599648;                  // 10240
constexpr size_t OFF_PART  = 609888;                  // 28672 floats
constexpr size_t PART_SZ   = 28672;
constexpr size_t OFF_HALF  = OFF_PART + PART_SZ;      // u16 arena base (float offset)

constexpr size_t HA = 0;                              // fm0/fm2
constexpr size_t HB = 3145728;                        // fm1/fm3 ; layer4: fc4 as f32
constexpr size_t HG = 9437184;                        // g1..g4
constexpr size_t HP = HG + 3145728;                   // fmp1/fmp2 (upper half of G)

// output element offsets (float32)
constexpr size_t OUT0 = 0;
constexpr size_t OUT1 = OUT0 + (size_t)Bz*N0*C0;
constexpr size_t OUT2 = OUT1 + (size_t)Bz*N0*C1;
constexpr size_t OUT3 = OUT2 + (size_t)Bz*N1*C2;
constexpr size_t OUT4 = OUT3 + (size_t)Bz*N1*C3;

DEV float b2f(u16 v) { return __uint_as_float(((unsigned int)v) << 16); }
DEV u16 f2b(float f) {
  unsigned int u = __float_as_uint(f);
  unsigned int lsb = (u >> 16) & 1u;
  return (u16)((u + 0x7fffu + lsb) >> 16);
}
DEV unsigned packb(float a, float b) {
  return (unsigned)f2b(a) | ((unsigned)f2b(b) << 16);
}

DEV u64 shflx64(u64 v, int m) {
  int lo = __shfl_xor((int)(unsigned)v, m, 64);
  int hi = __shfl_xor((int)(unsigned)(v >> 32), m, 64);
  return ((u64)(unsigned)hi << 32) | (unsigned)lo;
}
DEV int mbcnt64(u64 m) {
  return __builtin_amdgcn_mbcnt_hi((unsigned)(m >> 32),
         __builtin_amdgcn_mbcnt_lo((unsigned)m, 0));
}

DEV void st12(float* dst, const float* v) {
  float4 a{v[0],v[1],v[2],v[3]}, b{v[4],v[5],v[6],v[7]}, c{v[8],v[9],v[10],v[11]};
  ((float4*)dst)[0] = a; ((float4*)dst)[1] = b; ((float4*)dst)[2] = c;
}
DEV void st12(u16* dst, const float* v) {
  uint2 a{packb(v[0],v[1]), packb(v[2],v[3])};
  uint2 b{packb(v[4],v[5]), packb(v[6],v[7])};
  uint2 c{packb(v[8],v[9]), packb(v[10],v[11])};
  ((uint2*)dst)[0] = a; ((uint2*)dst)[1] = b; ((uint2*)dst)[2] = c;
}

// ---------------- convert all inputs -> f32 (self dtype-detect, zero partials) ----------------
struct InPtrs { const void* p[24]; };

__global__ void eq_convert_all(InPtrs in, float* ws) {
  __shared__ int sflag;
  {
    const u16* v = (const u16*)in.p[0];
    if (threadIdx.x < 64) {
      int bad = 0;
      #pragma unroll
      for (int j = 0; j < 4; ++j) {
        unsigned u = v[threadIdx.x*4 + j];
        int ex = (u >> 7) & 0xFF;
        bad += (((u & 0x7FFFu) != 0u) && (ex < 64 || ex > 191)) ? 1 : 0;
      }
      int tot = bad;
      #pragma unroll
      for (int s = 32; s > 0; s >>= 1) tot += __shfl_xor(tot, s, 64);
      if (threadIdx.x == 0) sflag = (tot >= 8) ? 1 : 0;   // 1 => inputs are f32
    }
    __syncthreads();
  }
  int f32mode = sflag;
  int t = blockIdx.x * blockDim.x + threadIdx.x;
  if (t < Bz*N0) {      // one thread per point; w = |p|^2
    float x, y, z;
    if (f32mode) { const float* v = (const float*)in.p[0]; x=v[t*3]; y=v[t*3+1]; z=v[t*3+2]; }
    else { const u16* v = (const u16*)in.p[0]; x=b2f(v[t*3]); y=b2f(v[t*3+1]); z=b2f(v[t*3+2]); }
    float4 o; o.x=x; o.y=y; o.z=z; o.w=(x*x + y*y) + z*z;
    ((float4*)(ws + OFF_V0F))[t] = o;
    int b = t / N0, i = t % N0;
    if ((i & 3) == 0)  ((float4*)(ws + OFF_V1F))[b*N1 + (i >> 2)] = o;
    if ((i & 15) == 0) ((float4*)(ws + OFF_V2F))[b*N2 + (i >> 4)] = o;
    return;
  }
  int r = t - Bz*N0;
  if (r >= 351312) {    // tail range zeroes bn partials
    int z = r - 351312;
    if (z < (int)PART_SZ) ws[OFF_PART + z] = 0.f;
    return;
  }
  const int cnt[23] = {1152, 36,2048,64,2048, 36,8192,128,8192,
                       36,32768,256,32768, 36,131072,512,131072,
                       64,64,128,128,256,256};
  const size_t off[23] = {OFF_K0F,
    OFF_DIRS+0,   OFF_WC+0,     OFF_BC+0,   OFF_WS+0,
    OFF_DIRS+36,  OFF_WC+2048,  OFF_BC+64,  OFF_WS+2048,
    OFF_DIRS+72,  OFF_WC+10240, OFF_BC+192, OFF_WS+10240,
    OFF_DIRS+108, OFF_WC+43008, OFF_BC+448, OFF_WS+43008,
    OFF_BN+0, OFF_BN+64, OFF_BN+128, OFF_BN+256, OFF_BN+384, OFF_BN+640};
  for (int i = 0; i < 23; ++i) {
    if (r < cnt[i]) {
      float val = f32mode ? ((const float*)in.p[i+1])[r] : b2f(((const u16*)in.p[i+1])[r]);
      ws[off[i] + r] = val;
      return;
    }
    r -= cnt[i];
  }
}

// ---------------- KNN body (v4 logic as device fn; smem passed in) ----------------
template<int NPTS>
DEV void knn_body(int blk, const float4* __restrict__ vf, int* __restrict__ idx_out,
                  char* smem) {
  constexpr int CPL = NPTS/64;
  constexpr int TILE = (NPTS < 512) ? NPTS : 512;
  constexpr int NT = NPTS / TILE;
  float4* tile = (float4*)smem;
  u64* selw_base = (u64*)(smem + TILE*16);
  int* extr_base = (int*)(smem + TILE*16 + 4*64*8);
  int wave = threadIdx.x >> 6, lane = threadIdx.x & 63;
  int tid = threadIdx.x;
  u64* selw = selw_base + wave*64;
  int* extrw = extr_base + wave*24;
  int qid = blk*4 + wave;
  int b = qid / NPTS, q = qid % NPTS;
  const float4* vb = vf + (size_t)b*NPTS;
  float4 vq = vb[q];
  const unsigned DINF = 0xFFFFFFFFu;
  unsigned d1=DINF, d2=DINF, d3=DINF, d4=DINF;
  int i1=0x3FFFFFFF, i2=0x3FFFFFFF, i3=0x3FFFFFFF, i4=0x3FFFFFFF;
  for (int tt = 0; tt < NT; ++tt) {
    __syncthreads();
    for (int i = tid; i < TILE; i += 256) tile[i] = vb[tt*TILE + i];
    __syncthreads();
    #pragma unroll 4
    for (int j = 0; j < TILE/64; ++j) {
      int cl = j*64 + lane;
      float4 vc = tile[cl];
      int c = tt*TILE + cl;
      float dt = (vq.x*vc.x + vq.y*vc.y) + vq.z*vc.z;
      float d = (vq.w + vc.w) - 2.0f*dt;
      unsigned u = __float_as_uint(d);
      unsigned ud = u ^ ((unsigned)(((int)u) >> 31) | 0x80000000u);  // monotone
      bool lt1 = ud < d1, lt2 = ud < d2, lt3 = ud < d3, lt4 = ud < d4;
      d4 = lt3 ? d3 : (lt4 ? ud : d4);  i4 = lt3 ? i3 : (lt4 ? c : i4);
      d3 = lt2 ? d2 : (lt3 ? ud : d3);  i3 = lt2 ? i2 : (lt3 ? c : i3);
      d2 = lt1 ? d1 : (lt2 ? ud : d2);  i2 = lt1 ? i1 : (lt2 ? c : i2);
      d1 = lt1 ? ud : d1;               i1 = lt1 ? c  : i1;
    }
  }
  unsigned p = 0;
  for (int bit = 31; bit >= 0; --bit) {
    unsigned T = p | (1u << bit);
    u64 m1 = __ballot(d1 < T), m2 = __ballot(d2 < T);
    u64 m3 = __ballot(d3 < T), m4 = __ballot(d4 < T);
    int cnt = __popcll(m1) + __popcll(m2) + __popcll(m3) + __popcll(m4);
    if (cnt < KNN+1) p = T;
  }
  size_t obase = (size_t)qid*KNN;
  bool need_fb = false;
  if (CPL > 4) {
    need_fb = (__ballot(d4 <= p) != 0ULL);
  }
  if (!need_fb) {
    bool p1 = d1 <= p, p2 = d2 <= p, p3 = d3 <= p, p4 = d4 <= p;
    u64 m1 = __ballot(p1), m2 = __ballot(p2), m3 = __ballot(p3), m4 = __ballot(p4);
    int c1 = __popcll(m1), c2 = __popcll(m2), c3 = __popcll(m3), c4 = __popcll(m4);
    int S = c1 + c2 + c3 + c4;
    if (S > 63) need_fb = true;
    else {
      if (p1) selw[mbcnt64(m1)] = ((u64)d1 << 32) | (unsigned)i1;
      if (p2) selw[c1 + mbcnt64(m2)] = ((u64)d2 << 32) | (unsigned)i2;
      if (p3) selw[c1 + c2 + mbcnt64(m3)] = ((u64)d3 << 32) | (unsigned)i3;
      if (p4) selw[c1 + c2 + c3 + mbcnt64(m4)] = ((u64)d4 << 32) | (unsigned)i4;
      if (lane < S) {
        u64 mykey = selw[lane];
        int rank = 0;
        for (int j = 0; j < S; ++j) rank += (selw[j] < mykey) ? 1 : 0;
        if (rank >= 1 && rank <= KNN)
          idx_out[obase + rank - 1] = (int)(unsigned)(mykey & 0xFFFFFFFFu);
      }
    }
  }
  if (need_fb) {
    const u64 KINF = ~0ULL;
    u64 k1 = ((u64)d1 << 32) | (unsigned)i1;
    u64 k2 = ((u64)d2 << 32) | (unsigned)i2;
    u64 k3 = ((u64)d3 << 32) | (unsigned)i3;
    u64 k4 = ((u64)d4 << 32) | (unsigned)i4;
    for (int r = 0; r < KNN+1; ++r) {
      u64 g = k1;
      #pragma unroll
      for (int s = 32; s; s >>= 1) { u64 o = shflx64(g, s); g = (o < g) ? o : g; }
      int gidx = (int)(g & 0xFFFFFFFFu);
      if (lane == 0) {
        extrw[r] = gidx;
        if (r > 0) idx_out[obase + r - 1] = gidx;
      }
      if (r < KNN && lane == (gidx & 63)) {
        k1 = k2; k2 = k3; k3 = k4; k4 = KINF;
        if (k1 == KINF) {
          for (int j = 0; j < CPL; ++j) {
            int c = j*64 + lane;
            float4 vc = vb[c];
            float dt = (vq.x*vc.x + vq.y*vc.y) + vq.z*vc.z;
            float d = (vq.w + vc.w) - 2.0f*dt;
            unsigned u = __float_as_uint(d);
            unsigned ud = u ^ ((unsigned)(((int)u) >> 31) | 0x80000000u);
            u64 k = ((u64)ud << 32) | (unsigned)c;
            bool ex = false;
            for (int e = 0; e <= r; ++e) ex |= (extrw[e] == c);
            if (!ex) {
              bool lt1 = k < k1, lt2 = k < k2, lt3 = k < k3, lt4 = k < k4;
              k4 = lt3 ? k3 : (lt4 ? k : k4);
              k3 = lt2 ? k2 : (lt3 ? k : k3);
              k2 = lt1 ? k1 : (lt2 ? k : k2);
              k1 = lt1 ? k  : k1;
            }
          }
        }
      }
    }
  }
}

// ---------------- fused KNN: all 3 levels in one dispatch ----------------
__global__ __launch_bounds__(256) void eq_knn_all(
    const float4* __restrict__ v0, int* __restrict__ i0,
    const float4* __restrict__ v1, int* __restrict__ i1,
    const float4* __restrict__ v2, int* __restrict__ i2) {
  __shared__ __align__(16) char smem[512*16 + 4*64*8 + 4*24*4];
  int blk = blockIdx.x;
  constexpr int NB0 = Bz*N0/4, NB1 = Bz*N1/4;
  if (blk < NB0)            knn_body<N0>(blk, v0, i0, smem);
  else if (blk < NB0+NB1)   knn_body<N1>(blk - NB0, v1, i1, smem);
  else                      knn_body<N2>(blk - NB0 - NB1, v2, i2, smem);
}

// ---------------- conv_surface + relu + fea_of(fm0), vectorized stores ----------------
__global__ __launch_bounds__(128) void eq_conv_surface(
    const float4* __restrict__ v0f, const int* __restrict__ idx0,
    const float* __restrict__ K0f, u16* __restrict__ fm0, float* __restrict__ out0) {
  int bq = blockIdx.x;          // b*N0 + q
  int b = bq >> 12;
  __shared__ float dk[KNN][3];
  __shared__ float row[C0*NA];
  int tid = threadIdx.x;
  if (tid < KNN) {
    int m = idx0[(size_t)bq*KNN + tid];
    float4 vq = v0f[bq];
    float4 vm = v0f[(size_t)b*N0 + m];
    float dx = vm.x - vq.x, dy = vm.y - vq.y, dz = vm.z - vq.z;
    float nrm = sqrtf((dx*dx + dy*dy) + dz*dz) + 1e-8f;
    dk[tid][0] = dx/nrm; dk[tid][1] = dy/nrm; dk[tid][2] = dz/nrm;
  }
  __syncthreads();
  for (int t4 = tid; t4 < C0*NA/4; t4 += 128) {
    const float* kd = K0f + (size_t)t4*12;
    float4 k0 = *(const float4*)(kd);
    float4 k1 = *(const float4*)(kd + 4);
    float4 k2 = *(const float4*)(kd + 8);
    float m0=0.f, m1=0.f, m2=0.f, m3=0.f;   // relu then max => >= 0
    #pragma unroll
    for (int k = 0; k < KNN; ++k) {
      float dx = dk[k][0], dy = dk[k][1], dz = dk[k][2];
      m0 = fmaxf(m0, (dx*k0.x + dy*k0.y) + dz*k0.z);
      m1 = fmaxf(m1, (dx*k0.w + dy*k1.x) + dz*k1.y);
      m2 = fmaxf(m2, (dx*k1.z + dy*k1.w) + dz*k2.x);
      m3 = fmaxf(m3, (dx*k2.y + dy*k2.z) + dz*k2.w);
    }
    uint2 r; r.x = packb(m0, m1); r.y = packb(m2, m3);
    ((uint2*)fm0)[(size_t)bq*(C0*NA/4) + t4] = r;
    row[4*t4+0] = m0; row[4*t4+1] = m1; row[4*t4+2] = m2; row[4*t4+3] = m3;
  }
  __syncthreads();
  if (tid < C0) {
    float m = row[tid*NA];
    #pragma unroll
    for (int a = 1; a < NA; ++a) m = fmaxf(m, row[tid*NA + a]);
    out0[(size_t)bq*C0 + tid] = m;
  }
}

// ---------------- linear v4: one matrix per block (blockIdx&1), o fast index ----
template<int CI, int CO, typename TO>
__global__ __launch_bounds__(256) void eq_linear4(
    const u16* __restrict__ in, const float* __restrict__ Wc,
    const float* __restrict__ Ws, const float* __restrict__ bias,
    TO* __restrict__ fc, u16* __restrict__ g) {
  constexpr int PPB = 512 / CO;
  constexpr int RS = CI*NA + 4;
  __shared__ float lds[PPB*RS];
  int tid = threadIdx.x;
  int mat = blockIdx.x & 1;
  int pt0 = (blockIdx.x >> 1) * PPB;
  constexpr int E = PPB*CI*NA;
  for (int t = tid; t < E; t += 256) {
    int pt = t / (CI*NA), r = t % (CI*NA);
    lds[pt*RS + r] = b2f(in[((size_t)(pt0+pt))*CI*NA + r]);
  }
  __syncthreads();
  constexpr int TPP = CO/2;
  int opair = tid % TPP, pt = tid / TPP;
  int o0 = opair*2;
  const float* W = mat ? Ws : Wc;
  const float* row = lds + pt*RS;
  float a0[NA], a1[NA];
  #pragma unroll
  for (int a = 0; a < NA; ++a) { a0[a]=0.f; a1[a]=0.f; }
  #pragma unroll 4
  for (int c = 0; c < CI; ++c) {
    float2 w2 = *(const float2*)(W + (size_t)c*CO + o0);
    float4 i0 = *(const float4*)(row + c*NA);
    float4 i1 = *(const float4*)(row + c*NA + 4);
    float4 i2 = *(const float4*)(row + c*NA + 8);
    float iv[NA] = {i0.x,i0.y,i0.z,i0.w, i1.x,i1.y,i1.z,i1.w, i2.x,i2.y,i2.z,i2.w};
    #pragma unroll
    for (int a = 0; a < NA; ++a) {
      a0[a] += iv[a]*w2.x; a1[a] += iv[a]*w2.y;
    }
  }
  size_t ptg = pt0 + pt;
  if (mat == 0) {
    float b0 = bias[o0], b1 = bias[o0+1];
    #pragma unroll
    for (int a = 0; a < NA; ++a) { a0[a] += b0; a1[a] += b1; }
    st12(fc + ((size_t)ptg*CO + o0)*NA, a0);
    st12(fc + ((size_t)ptg*CO + o0 + 1)*NA, a1);
  } else {
    st12(g + ((size_t)ptg*CO + o0)*NA, a0);
    st12(g + ((size_t)ptg*CO + o0 + 1)*NA, a1);
  }
}

// ---------------- fsmax + fused BN partial stats (unroll 5, f4 th loads) ----------------
__global__ __launch_bounds__(256) void eq_fsmax(
    const u16* __restrict__ g, const float4* __restrict__ vf,
    const float* __restrict__ dirs, const int* __restrict__ idx,
    u16* __restrict__ out, float* __restrict__ part, int npts, int co) {
  int bq = blockIdx.x;
  int b = bq / npts;
  __shared__ float th[KNN*NA];
  __shared__ float dk[KNN][3];
  __shared__ int nb[KNN];
  __shared__ float sstat[2][C3];     // co <= 256
  int tid = threadIdx.x;
  if (tid < KNN) {
    int m = idx[(size_t)bq*KNN + tid];
    nb[tid] = m;
    float4 vq = vf[bq];
    float4 vm = vf[(size_t)b*npts + m];
    float dx = vm.x - vq.x, dy = vm.y - vq.y, dz = vm.z - vq.z;
    float nrm = sqrtf((dx*dx + dy*dy) + dz*dz) + 1e-8f;
    dk[tid][0] = dx/nrm; dk[tid][1] = dy/nrm; dk[tid][2] = dz/nrm;
  }
  sstat[0][tid] = 0.f; sstat[1][tid] = 0.f;
  __syncthreads();
  if (tid < KNN*NA) {
    int k = tid / NA, a = tid % NA;
    float s = (dk[k][0]*dirs[a*3] + dk[k][1]*dirs[a*3+1]) + dk[k][2]*dirs[a*3+2];
    th[tid] = fmaxf(s, 0.f);
  }
  __syncthreads();
  int quarter = co*NA/4;
  uint2* dst = (uint2*)(out + (size_t)bq*co*NA);
  const uint2* gb = (const uint2*)(g + (size_t)b*npts*co*NA);
  for (int t4 = tid; t4 < quarter; t4 += 256) {
    int a = (4*t4) % NA;          // 0, 4, or 8 — quad never straddles an o-row
    const float* tha = th + a;
    float m0=-3.0e38f, m1=-3.0e38f, m2=-3.0e38f, m3=-3.0e38f;
    #pragma unroll 5
    for (int k = 0; k < KNN; ++k) {
      uint2 pv = gb[(size_t)nb[k]*quarter + t4];
      float4 tv = *(const float4*)(tha + k*NA);   // 16B-aligned: a%4==0, 48|k*NA*4
      m0 = fmaxf(m0, tv.x*b2f((u16)(pv.x)));
      m1 = fmaxf(m1, tv.y*b2f((u16)(pv.x >> 16)));
      m2 = fmaxf(m2, tv.z*b2f((u16)(pv.y)));
      m3 = fmaxf(m3, tv.w*b2f((u16)(pv.y >> 16)));
    }
    uint2 d = dst[t4];
    float v0 = b2f((u16)d.x) + m0;
    float v1 = b2f((u16)(d.x >> 16)) + m1;
    float v2 = b2f((u16)d.y) + m2;
    float v3 = b2f((u16)(d.y >> 16)) + m3;
    uint2 r; r.x = packb(v0, v1); r.y = packb(v2, v3);
    dst[t4] = r;
    int ch = t4 / 3;              // NA/4 = 3 quads per channel
    atomicAdd(&sstat[0][ch], (v0 + v1) + (v2 + v3));
    atomicAdd(&sstat[1][ch], (v0*v0 + v1*v1) + (v2*v2 + v3*v3));
  }
  __syncthreads();
  if (tid < co) {
    float* pg = part + (size_t)(bq & (BNG-1))*2*co;
    atomicAdd(&pg[tid], sstat[0][tid]);
    atomicAdd(&pg[co + tid], sstat[1][tid]);
  }
}

// ---------------- layer4: fsmax + fea_of fused, channel-split, vectorized ----------------
template<int SPL>
__global__ __launch_bounds__(256) void eq_fsmax_fea(
    const u16* __restrict__ g, const float* __restrict__ fcin,
    const float4* __restrict__ vf, const float* __restrict__ dirs,
    const int* __restrict__ idx, float* __restrict__ outfea,
    int npts, int co) {
  constexpr int CHUNK = C4 / SPL;
  int part = blockIdx.x % SPL;
  int bq = blockIdx.x / SPL;
  int b = bq / npts;
  __shared__ float th[KNN*NA];
  __shared__ float dk[KNN][3];
  __shared__ int nb[KNN];
  __shared__ float row[CHUNK*NA];
  int tid = threadIdx.x;
  if (tid < KNN) {
    int m = idx[(size_t)bq*KNN + tid];
    nb[tid] = m;
    float4 vq = vf[bq];
    float4 vm = vf[(size_t)b*npts + m];
    float dx = vm.x - vq.x, dy = vm.y - vq.y, dz = vm.z - vq.z;
    float nrm = sqrtf((dx*dx + dy*dy) + dz*dz) + 1e-8f;
    dk[tid][0] = dx/nrm; dk[tid][1] = dy/nrm; dk[tid][2] = dz/nrm;
  }
  __syncthreads();
  if (tid < KNN*NA) {
    int k = tid / NA, a = tid % NA;
    float s = (dk[k][0]*dirs[a*3] + dk[k][1]*dirs[a*3+1]) + dk[k][2]*dirs[a*3+2];
    th[tid] = fmaxf(s, 0.f);
  }
  __syncthreads();
  int o0 = part * CHUNK;
  const float4* fcr = (const float4*)(fcin + ((size_t)bq*co + o0)*NA);
  const uint2* gb = (const uint2*)(g + (size_t)b*npts*co*NA + (size_t)o0*NA);
  int gquarter = co*NA/4;
  for (int t4 = tid; t4 < CHUNK*NA/4; t4 += 256) {
    int a = (4*t4) % NA;
    const float* tha = th + a;
    float m0=-3.0e38f, m1=-3.0e38f, m2=-3.0e38f, m3=-3.0e38f;
    #pragma unroll 5
    for (int k = 0; k < KNN; ++k) {
      uint2 pv = gb[(size_t)nb[k]*gquarter + t4];
      float4 tv = *(const float4*)(tha + k*NA);
      m0 = fmaxf(m0, tv.x*b2f((u16)(pv.x)));
      m1 = fmaxf(m1, tv.y*b2f((u16)(pv.x >> 16)));
      m2 = fmaxf(m2, tv.z*b2f((u16)(pv.y)));
      m3 = fmaxf(m3, tv.w*b2f((u16)(pv.y >> 16)));
    }
    float4 fc4 = fcr[t4];
    row[4*t4+0] = fc4.x + m0;
    row[4*t4+1] = fc4.y + m1;
    row[4*t4+2] = fc4.z + m2;
    row[4*t4+3] = fc4.w + m3;
  }
  __syncthreads();
  for (int o = tid; o < CHUNK; o += 256) {
    float m = row[o*NA];
    #pragma unroll
    for (int a = 1; a < NA; ++a) m = fmaxf(m, row[o*NA + a]);
    outfea[(size_t)bq*co + o0 + o] = m;
  }
}

// ---------------- normalize + relu (in place) + fea_of (folds BNG partials) ----------------
__global__ __launch_bounds__(256) void eq_bnrelu_fea(
    u16* __restrict__ fm, const float* __restrict__ part,
    const float* __restrict__ gamma, const float* __restrict__ beta,
    float* __restrict__ outfea, int npts, int co) {
  int bq = blockIdx.x;
  int tid = threadIdx.x;
  __shared__ float sc[C3], sh[C3];
  __shared__ float row[C3*NA];
  for (int o = tid; o < co; o += 256) {
    float s = 0.f, s2 = 0.f;
    for (int g = 0; g < BNG; ++g) {
      s  += part[(size_t)g*2*co + o];
      s2 += part[(size_t)g*2*co + co + o];
    }
    float cnt = (float)(Bz*npts*NA);
    float mean = s / cnt;
    float var = fmaxf(s2 / cnt - mean*mean, 0.f);
    float inv = 1.0f / sqrtf(var + 1e-5f);
    sc[o] = gamma[o] * inv;
    sh[o] = beta[o] - mean * gamma[o] * inv;
  }
  __syncthreads();
  uint2* p = (uint2*)(fm + (size_t)bq*co*NA);
  int quarter = co*NA/4;
  for (int t4 = tid; t4 < quarter; t4 += 256) {
    int o = (4*t4) / NA;            // quad never straddles o-row
    float s = sc[o], h = sh[o];
    uint2 pv = p[t4];
    float v0 = fmaxf(b2f((u16)pv.x)*s + h, 0.f);
    float v1 = fmaxf(b2f((u16)(pv.x >> 16))*s + h, 0.f);
    float v2 = fmaxf(b2f((u16)pv.y)*s + h, 0.f);
    float v3 = fmaxf(b2f((u16)(pv.y >> 16))*s + h, 0.f);
    uint2 r; r.x = packb(v0, v1); r.y = packb(v2, v3);
    p[t4] = r;
    row[4*t4+0] = v0; row[4*t4+1] = v1; row[4*t4+2] = v2; row[4*t4+3] = v3;
  }
  __syncthreads();
  for (int o = tid; o < co; o += 256) {
    float m = row[o*NA];
    #pragma unroll
    for (int a = 1; a < NA; ++a) m = fmaxf(m, row[o*NA + a]);
    outfea[(size_t)bq*co + o] = m;
  }
}

// ---------------- pool (vectorized): fmp = max(fm[4j], max_k fm[nb]) ----------------
__global__ __launch_bounds__(256) void eq_pool(
    const u16* __restrict__ fm, const int* __restrict__ idx,
    u16* __restrict__ fmp, int npts, int c) {
  int ns = npts / 4;
  int bj = blockIdx.x;
  int b = bj / ns, j = bj % ns;
  int q = 4*j;
  size_t bq = (size_t)b*npts + q;
  __shared__ int nb[4];
  if (threadIdx.x < 4) nb[threadIdx.x] = idx[bq*KNN + threadIdx.x];
  __syncthreads();
  int quarter = c*NA/4;
  const uint2* base = (const uint2*)(fm + (size_t)b*npts*c*NA);
  const uint2* p0 = base + (size_t)q*quarter;
  uint2* dst = (uint2*)(fmp + (size_t)bj*c*NA);
  for (int t4 = threadIdx.x; t4 < quarter; t4 += 256) {
    uint2 v = p0[t4];
    float m0 = b2f((u16)v.x), m1 = b2f((u16)(v.x >> 16));
    float m2 = b2f((u16)v.y), m3 = b2f((u16)(v.y >> 16));
    #pragma unroll
    for (int kk = 0; kk < 4; ++kk) {
      uint2 w = base[(size_t)nb[kk]*quarter + t4];
      m0 = fmaxf(m0, b2f((u16)w.x));
      m1 = fmaxf(m1, b2f((u16)(w.x >> 16)));
      m2 = fmaxf(m2, b2f((u16)w.y));
      m3 = fmaxf(m3, b2f((u16)(w.y >> 16)));
    }
    uint2 r; r.x = packb(m0, m1); r.y = packb(m2, m3);
    dst[t4] = r;
  }
}

// ---------------- host orchestration ----------------
extern "C" void kernel_launch(void* const* d_in, const int* in_sizes, int n_in,
                              void* d_out, int out_size, void* d_ws, size_t ws_size,
                              hipStream_t stream) {
  float* ws = (float*)d_ws;
  float* out = (float*)d_out;
  u16* arena = (u16*)(ws + OFF_HALF);

  InPtrs ip;
  for (int i = 0; i < 24; ++i) ip.p[i] = d_in[i];

  float4* v0f = (float4*)(ws + OFF_V0F);
  float4* v1f = (float4*)(ws + OFF_V1F);
  float4* v2f = (float4*)(ws + OFF_V2F);
  int* idx0 = (int*)(ws + OFF_IDX0);
  int* idx1 = (int*)(ws + OFF_IDX1);
  int* idx2 = (int*)(ws + OFF_IDX2);
  u16* bufA = arena + HA;            // fm0 -> fm2
  u16* bufB = arena + HB;            // fm1 -> fm3
  float* fc4f = (float*)(arena + HB);// layer4 fc carrier (fm3 dead by then)
  u16* bufG = arena + HG;            // g (Ws-transformed)
  u16* bufP = arena + HP;            // fmp1/fmp2 (upper half of G)
  float* partA = ws + OFF_PART;            // 32 x 2*C1
  float* partB = ws + OFF_PART + 4096;     // 32 x 2*C2
  float* partC = ws + OFF_PART + 12288;    // 32 x 2*C3
  const float* DIRS = ws + OFF_DIRS;

  // 0) convert all inputs (self dtype-detect; zeroes bn partials; v1f/v2f subsamples)
  {
    int total = Bz*N0 + 351312 + (int)PART_SZ;
    eq_convert_all<<<(total + 255)/256, 256, 0, stream>>>(ip, ws);
  }

  // 1) all 3 KNN levels in one dispatch (all depend only on convert)
  eq_knn_all<<<Bz*N0/4 + Bz*N1/4 + Bz*N2/4, 256, 0, stream>>>(v0f, idx0, v1f, idx1, v2f, idx2);
  eq_conv_surface<<<Bz*N0, 128, 0, stream>>>(v0f, idx0, ws + OFF_K0F, bufA, out + OUT0);

  // 2) layer1: fm0(bufA,C0) -> fm1(bufB,C1) at N0
  eq_linear4<C0, C1, u16><<<(Bz*N0/8)*2, 256, 0, stream>>>(bufA, ws + OFF_WC + 0, ws + OFF_WS + 0,
                                                           ws + OFF_BC + 0, bufB, bufG);
  eq_fsmax<<<Bz*N0, 256, 0, stream>>>(bufG, v0f, DIRS + 0, idx0, bufB, partA, N0, C1);
  eq_bnrelu_fea<<<Bz*N0, 256, 0, stream>>>(bufB, partA, ws + OFF_BN + 0, ws + OFF_BN + 64,
                                           out + OUT1, N0, C1);

  // 3) pool1: fm1(bufB) -> fmp1(bufP,C1) at N1
  eq_pool<<<Bz*N1, 256, 0, stream>>>(bufB, idx0, bufP, N0, C1);

  // 4) layer2: fmp1(bufP,C1) -> fm2(bufA,C2) at N1
  eq_linear4<C1, C2, u16><<<(Bz*N1/4)*2, 256, 0, stream>>>(bufP, ws + OFF_WC + 2048, ws + OFF_WS + 2048,
                                                           ws + OFF_BC + 64, bufA, bufG);
  eq_fsmax<<<Bz*N1, 256, 0, stream>>>(bufG, v1f, DIRS + 36, idx1, bufA, partB, N1, C2);
  eq_bnrelu_fea<<<Bz*N1, 256, 0, stream>>>(bufA, partB, ws + OFF_BN + 128, ws + OFF_BN + 256,
                                           out + OUT2, N1, C2);

  // 5) layer3: fm2(bufA,C2) -> fm3(bufB,C3) at N1
  eq_linear4<C2, C3, u16><<<(Bz*N1/2)*2, 256, 0, stream>>>(bufA, ws + OFF_WC + 10240, ws + OFF_WS + 10240,
                                                           ws + OFF_BC + 192, bufB, bufG);
  eq_fsmax<<<Bz*N1, 256, 0, stream>>>(bufG, v1f, DIRS + 72, idx1, bufB, partC, N1, C3);
  eq_bnrelu_fea<<<Bz*N1, 256, 0, stream>>>(bufB, partC, ws + OFF_BN + 384, ws + OFF_BN + 640,
                                           out + OUT3, N1, C3);

  // 6) pool2: fm3(bufB,C3) -> fmp2(bufP,C3) at N2
  eq_pool<<<Bz*N2, 256, 0, stream>>>(bufB, idx1, bufP, N1, C3);

  // 7) layer4: fmp2(bufP,C3) -> fc4(f32) + g; fused fsmax+fea (4-way split) -> out4
  eq_linear4<C3, C4, float><<<(Bz*N2)*2, 256, 0, stream>>>(bufP, ws + OFF_WC + 43008, ws + OFF_WS + 43008,
                                                           ws + OFF_BC + 448, fc4f, bufG);
  eq_fsmax_fea<4><<<Bz*N2*4, 256, 0, stream>>>(bufG, fc4f, v2f, DIRS + 108, idx2, out + OUT4, N2, C4);
}